// Round 14
// baseline (157.722 us; speedup 1.0000x reference)
//
#include <hip/hip_runtime.h>
#include <hip/hip_bf16.h>

// LUTLayerBasic: out[b] = sum_d W[d*16 + ch(b,d)], ch = 4 sign bits of gathered x.
// R14 = R12 with ONE change: 4x the blocks, thinner waves, for TLP.
//  - wave = 32 rows x 32 cols (rf=1, acc=16 regs), block = 4 waves stacked in
//    M (128 rows x 32 cols), grid = 16 mBlk x 64 strips = 1024 blocks
//    = 4 blocks/CU = 4 waves/SIMD (R12 was 2 waves/SIMD, grid-limited).
//  - per wave-step: 2 mkA + 2 MFMA + 3 loads; SIMD matrix 292 > VALU 224 cyc.
//  - depth-4 register prefetch, KP=1, plain stores, no LDS, no barriers.
//
// Dims: B=2048, N_IN=2048, D=1024, A=4, O=2048, C=16, K=N_LUT=16384.

typedef __attribute__((ext_vector_type(4))) int i32x4;
typedef __attribute__((ext_vector_type(16))) int i32x16;
typedef __attribute__((ext_vector_type(4))) float f32x4;

__device__ __forceinline__ bool anchors_is_i64(const int* a) {
  int v = 0;
#pragma unroll
  for (int i = 0; i < 32; ++i) v |= a[2 * i + 1];
  return v == 0;
}

__device__ __forceinline__ int ld_anchor(const int* a, int i, bool is64) {
  return is64 ? a[2 * i] : a[i];
}

// One-hot A fragment: 16 bytes, byte[ch] = 1 (ch in [0,16)). R7/R8-verified.
__device__ __forceinline__ i32x4 mkA(unsigned ch) {
  unsigned long long v = 1ull << ((ch << 3) & 63u);
  union { unsigned long long q[2]; i32x4 v4; } u;
  u.q[0] = (ch < 8u) ? v : 0ull;
  u.q[1] = (ch < 8u) ? 0ull : v;
  return u.v4;
}

// ---------------------------------------------------------------------------
// Kernel 0: transpose + bitpack. xbT[n][s] = (x[s][n] > 0) as byte.
// ---------------------------------------------------------------------------
__global__ __launch_bounds__(256) void k_bits(const float* __restrict__ x,
                                              unsigned char* __restrict__ xbT) {
  __shared__ unsigned char t[64][65];
  const int tid = threadIdx.x;
  const int tr = blockIdx.x * 64, tc = blockIdx.y * 64;
  const int c = tid & 63, r0 = tid >> 6;
#pragma unroll
  for (int j = 0; j < 16; ++j) {
    int r = r0 + j * 4;
    t[c][r] = x[(size_t)(tr + r) * 2048 + tc + c] > 0.0f ? 1 : 0;
  }
  __syncthreads();
#pragma unroll
  for (int j = 0; j < 16; ++j) {
    int n = r0 + j * 4;
    xbT[(size_t)(tc + n) * 2048 + tr + c] = t[n][c];
  }
}

// ---------------------------------------------------------------------------
// Kernel 1: channel quads in GEMM-register layout. For sample s decomposed as
// s = g*128 + rf*32 + l (g row-group, rf row-frag, l lane):
//   chR[((kq*16 + g)*32 + l) * 4 + rf] = ch(s,4kq..4kq+3) packed bytes.
// ---------------------------------------------------------------------------
__global__ __launch_bounds__(256) void k_channels3(const unsigned char* __restrict__ xbT,
                                                   const int* __restrict__ anc,
                                                   unsigned* __restrict__ chR) {
  const int s = blockIdx.x * 256 + threadIdx.x;  // gridDim.x = 8
  const int kq = blockIdx.y;                     // [0, 256)
  const bool is64 = anchors_is_i64(anc);
  unsigned word = 0;
#pragma unroll
  for (int di = 0; di < 4; ++di) {
    const int d = kq * 4 + di;
    unsigned ch = 0;
#pragma unroll
    for (int i = 0; i < 4; ++i) {
      int a = ld_anchor(anc, d * 4 + i, is64);
      ch |= (unsigned)xbT[(size_t)a * 2048 + s] << i;
    }
    word |= ch << (di * 8);
  }
  const int g = s >> 7, rf = (s >> 5) & 3, l = s & 31;
  chR[(((size_t)kq * 16 + g) * 32 + l) * 4 + rf] = word;
}

// ---------------------------------------------------------------------------
// Kernel 2: W (f32 [16384][2048]) -> i8 fragment-linear chunks:
//   chunk c_idx = (kt*64 + nc)*64 + l  (16 B), byte j:
//   Wq[(2kt + (l>>5))*16 + j][nc*32 + (l&31)],  Wq = round(W*127).
// ---------------------------------------------------------------------------
__global__ __launch_bounds__(256) void k_wfrag_i8(const float* __restrict__ W,
                                                  uint4* __restrict__ wfq) {
  const unsigned flat = blockIdx.x * 256 + threadIdx.x;  // [0, 2097152)
  const unsigned l = flat & 63u, nc = (flat >> 6) & 63u, kt = flat >> 12;
  const unsigned dd = 2u * kt + (l >> 5), col = nc * 32u + (l & 31u);
  const float* base = W + (size_t)(dd * 16u) * 2048u + col;
  unsigned wd[4];
#pragma unroll
  for (int wi = 0; wi < 4; ++wi) {
    unsigned v = 0;
#pragma unroll
    for (int bj = 0; bj < 4; ++bj) {
      float f = base[(size_t)(wi * 4 + bj) * 2048u];
      int q = (int)(f * 127.0f + 0.5f);
      q = q < 0 ? 0 : (q > 127 ? 127 : q);
      v |= (unsigned)q << (bj * 8);
    }
    wd[wi] = v;
  }
  uint4 o;
  o.x = wd[0]; o.y = wd[1]; o.z = wd[2]; o.w = wd[3];
  wfq[flat] = o;
}

// ---------------------------------------------------------------------------
// Kernel 3: zero-LDS streaming i8 GEMM, KP=1, depth-4 register pipeline.
// Block 128x32 (4 waves of 32 rows), wave 32x32 (rf=1), NB=256 BK64 steps.
// Grid 1024 (= 4 blocks/CU, 4 waves/SIMD). Plain stores.
// ---------------------------------------------------------------------------
__global__ __launch_bounds__(256, 4) void k_gemm(const uint4* __restrict__ wfq,
                                                 const unsigned* __restrict__ chR,
                                                 float* __restrict__ out) {
  constexpr int NB = 256;  // BK64 steps, full K
  constexpr int PD = 4;    // prefetch depth

  const int tid = threadIdx.x, lane = tid & 63;
  const int w = tid >> 6;  // wave index in M within block (= rf slot)
  const unsigned q = (unsigned)(lane >> 5), q8 = q << 3;

  // XCD decode (1024 = 8 XCD x 128): R12's proven pattern, 16 mBlk.
  const unsigned orig = blockIdx.x;
  const unsigned xcd = orig & 7u, slot = orig >> 3;   // slot [0,128)
  const unsigned strip = xcd * 8u + (slot & 7u);      // [0,64) col strip (32 cols)
  const unsigned mBlk = slot >> 3;                    // [0,16) 128-row block

  // W fragment pointer: chunk (kt*64 + nc)*64 + lane, nc = strip, kt = 2*kq.
  // Step stride (kq+1) = 8192 uint4; second K32 half at +4096.
  const uint4* wp0 = wfq + ((size_t)strip * 64u) + lane;
  const uint4* wp1 = wp0 + 4096;
  // Channel pointer: one dword per (kq, g=mBlk, lane&31, rf=w); step stride
  // = 16*32*4 = 2048 dwords.
  const unsigned* cp = chR + (((size_t)mBlk) * 32u + (lane & 31)) * 4u + (unsigned)w;

  i32x16 acc = {};

#define MFMA_I8(a, b, c) __builtin_amdgcn_mfma_i32_32x32x32_i8((a), (b), (c), 0, 0, 0)

  uint4 b0[PD], b1[PD];
  unsigned cw[PD];
#pragma unroll
  for (int i = 0; i < PD; ++i) {
    b0[i] = wp0[(size_t)i * 8192];
    b1[i] = wp1[(size_t)i * 8192];
    cw[i] = cp[(size_t)i * 2048];
  }

#define COMPUTE(i)                                                        \
  {                                                                       \
    const i32x4 vb0 = *(const i32x4*)&b0[i];                              \
    const i32x4 vb1 = *(const i32x4*)&b1[i];                              \
    __builtin_amdgcn_s_setprio(1);                                        \
    acc = MFMA_I8(mkA((cw[i] >> q8) & 15u), vb0, acc);                    \
    acc = MFMA_I8(mkA((cw[i] >> (16u + q8)) & 15u), vb1, acc);            \
    __builtin_amdgcn_s_setprio(0);                                        \
  }
  // Refill buffer i for step p+PD (clamped at tail -> dead reload).
#define REFILL(i, p)                                                      \
  {                                                                       \
    const int np = ((p) + PD < NB) ? (p) + PD : (p);                      \
    b0[i] = wp0[(size_t)np * 8192];                                       \
    b1[i] = wp1[(size_t)np * 8192];                                       \
    cw[i] = cp[(size_t)np * 2048];                                        \
  }

  for (int p = 0; p < NB; p += PD) {
    COMPUTE(0) REFILL(0, p)
    COMPUTE(1) REFILL(1, p + 1)
    COMPUTE(2) REFILL(2, p + 2)
    COMPUTE(3) REFILL(3, p + 3)
  }
#undef COMPUTE
#undef REFILL

  // Epilogue: plain stores. C/D 32x32 layout: col = lane&31,
  // row = (reg&3) + 8*(reg>>2) + 4*q, within the wave's 32-row block.
  const float scale = 1.0f / 127.0f;
  const int c = (int)strip * 32 + (lane & 31);
  const int r0 = (int)mBlk * 128 + w * 32 + (int)(q * 4u);
#pragma unroll
  for (int reg = 0; reg < 16; ++reg) {
    int r = r0 + (reg & 3) + 8 * (reg >> 2);
    out[(size_t)r * 2048 + c] = (float)acc[reg] * scale;
  }
}

// ---------------------------------------------------------------------------
// Fallback (ws too small): direct gather row-sum, one block per sample.
// ---------------------------------------------------------------------------
__global__ __launch_bounds__(256) void k_direct(const float* __restrict__ x,
                                                const int* __restrict__ anc,
                                                const float* __restrict__ W,
                                                float* __restrict__ out) {
  __shared__ unsigned rowoff[1024];
  const int b = blockIdx.x;
  const bool is64 = anchors_is_i64(anc);
  for (int d = threadIdx.x; d < 1024; d += 256) {
    unsigned ch = 0;
#pragma unroll
    for (int i = 0; i < 4; ++i) {
      int a = ld_anchor(anc, d * 4 + i, is64);
      ch |= (x[(size_t)b * 2048 + a] > 0.0f ? 1u : 0u) << i;
    }
    rowoff[d] = (unsigned)(d * 16 + ch) * 2048u;
  }
  __syncthreads();
  f32x4 a0 = {0.f, 0.f, 0.f, 0.f}, a1 = {0.f, 0.f, 0.f, 0.f};
  const int o0 = threadIdx.x * 4, o1 = 1024 + threadIdx.x * 4;
  for (int d = 0; d < 1024; ++d) {
    unsigned ro = rowoff[d];
    a0 += *(const f32x4*)(W + ro + o0);
    a1 += *(const f32x4*)(W + ro + o1);
  }
  *(f32x4*)(out + (size_t)b * 2048 + o0) = a0;
  *(f32x4*)(out + (size_t)b * 2048 + o1) = a1;
}

// ---------------------------------------------------------------------------
extern "C" void kernel_launch(void* const* d_in, const int* in_sizes, int n_in,
                              void* d_out, int out_size, void* d_ws, size_t ws_size,
                              hipStream_t stream) {
  const float* x = (const float*)d_in[0];
  const int* anc = (const int*)d_in[1];
  const float* W = (const float*)d_in[2];
  float* out = (float*)d_out;

  const size_t CHR_BYTES = 2ull * 1024 * 1024;   // chR: 256 x 16 x 32 uint4
  const size_t WFQ_BYTES = 32ull * 1024 * 1024;  // wfq: 2M x 16 B (i8)
  const size_t XBT_BYTES = 4ull * 1024 * 1024;   // xbT: 2048 x 2048 u8
  const size_t BASE = CHR_BYTES + WFQ_BYTES + XBT_BYTES;  // 38 MiB

  if (ws_size < BASE) {
    k_direct<<<2048, 256, 0, stream>>>(x, anc, W, out);
    return;
  }

  unsigned* chR = (unsigned*)d_ws;
  uint4* wfq = (uint4*)((char*)d_ws + CHR_BYTES);
  unsigned char* xbT = (unsigned char*)((char*)d_ws + CHR_BYTES + WFQ_BYTES);

  k_bits<<<dim3(32, 32), 256, 0, stream>>>(x, xbT);
  k_channels3<<<dim3(8, 256), 256, 0, stream>>>(xbT, anc, chR);
  k_wfrag_i8<<<8192, 256, 0, stream>>>(W, wfq);
  k_gemm<<<1024, 256, 0, stream>>>(wfq, chR, out);
}

// Round 15
// 128.819 us; speedup vs baseline: 1.2244x; 1.2244x over previous
//
#include <hip/hip_runtime.h>
#include <hip/hip_bf16.h>

// LUTLayerBasic: out[b] = sum_d W[d*16 + ch(b,d)], ch = 4 sign bits of gathered x.
// R15 = R12 (best: 102.2 us total) MINUS the per-step s_setprio wrapper.
// Theory: with ~2 waves/SIMD, setprio(1) around the MFMA cluster starves the
// co-wave's VALU (A-build) -> the two waves phase-lock (VALU together, MFMA
// together; R8's MfmaUtil 30 + VALUBusy 46, neither high). T5 catalog: setprio
// is negative on free-running GEMM loops (m190). Single-variable ablation.
//
// Dims: B=2048, N_IN=2048, D=1024, A=4, O=2048, C=16, K=N_LUT=16384.

typedef __attribute__((ext_vector_type(4))) int i32x4;
typedef __attribute__((ext_vector_type(16))) int i32x16;
typedef __attribute__((ext_vector_type(4))) float f32x4;

__device__ __forceinline__ bool anchors_is_i64(const int* a) {
  int v = 0;
#pragma unroll
  for (int i = 0; i < 32; ++i) v |= a[2 * i + 1];
  return v == 0;
}

__device__ __forceinline__ int ld_anchor(const int* a, int i, bool is64) {
  return is64 ? a[2 * i] : a[i];
}

// One-hot A fragment: 16 bytes, byte[ch] = 1 (ch in [0,16)). R7/R8-verified.
__device__ __forceinline__ i32x4 mkA(unsigned ch) {
  unsigned long long v = 1ull << ((ch << 3) & 63u);
  union { unsigned long long q[2]; i32x4 v4; } u;
  u.q[0] = (ch < 8u) ? v : 0ull;
  u.q[1] = (ch < 8u) ? 0ull : v;
  return u.v4;
}

// ---------------------------------------------------------------------------
// Kernel 0: transpose + bitpack. xbT[n][s] = (x[s][n] > 0) as byte.
// ---------------------------------------------------------------------------
__global__ __launch_bounds__(256) void k_bits(const float* __restrict__ x,
                                              unsigned char* __restrict__ xbT) {
  __shared__ unsigned char t[64][65];
  const int tid = threadIdx.x;
  const int tr = blockIdx.x * 64, tc = blockIdx.y * 64;
  const int c = tid & 63, r0 = tid >> 6;
#pragma unroll
  for (int j = 0; j < 16; ++j) {
    int r = r0 + j * 4;
    t[c][r] = x[(size_t)(tr + r) * 2048 + tc + c] > 0.0f ? 1 : 0;
  }
  __syncthreads();
#pragma unroll
  for (int j = 0; j < 16; ++j) {
    int n = r0 + j * 4;
    xbT[(size_t)(tc + n) * 2048 + tr + c] = t[n][c];
  }
}

// ---------------------------------------------------------------------------
// Kernel 1: channel quads in GEMM-register layout. For sample s decomposed as
// s = g*128 + rf*32 + l (g row-group, rf row-frag, l lane):
//   chR[((kq*16 + g)*32 + l) * 4 + rf] = ch(s,4kq..4kq+3) packed bytes.
// ---------------------------------------------------------------------------
__global__ __launch_bounds__(256) void k_channels3(const unsigned char* __restrict__ xbT,
                                                   const int* __restrict__ anc,
                                                   unsigned* __restrict__ chR) {
  const int s = blockIdx.x * 256 + threadIdx.x;  // gridDim.x = 8
  const int kq = blockIdx.y;                     // [0, 256)
  const bool is64 = anchors_is_i64(anc);
  unsigned word = 0;
#pragma unroll
  for (int di = 0; di < 4; ++di) {
    const int d = kq * 4 + di;
    unsigned ch = 0;
#pragma unroll
    for (int i = 0; i < 4; ++i) {
      int a = ld_anchor(anc, d * 4 + i, is64);
      ch |= (unsigned)xbT[(size_t)a * 2048 + s] << i;
    }
    word |= ch << (di * 8);
  }
  const int g = s >> 7, rf = (s >> 5) & 3, l = s & 31;
  chR[(((size_t)kq * 16 + g) * 32 + l) * 4 + rf] = word;
}

// ---------------------------------------------------------------------------
// Kernel 2: W (f32 [16384][2048]) -> i8 fragment-linear chunks:
//   chunk c_idx = (kt*64 + nc)*64 + l  (16 B), byte j:
//   Wq[(2kt + (l>>5))*16 + j][nc*32 + (l&31)],  Wq = round(W*127).
// ---------------------------------------------------------------------------
__global__ __launch_bounds__(256) void k_wfrag_i8(const float* __restrict__ W,
                                                  uint4* __restrict__ wfq) {
  const unsigned flat = blockIdx.x * 256 + threadIdx.x;  // [0, 2097152)
  const unsigned l = flat & 63u, nc = (flat >> 6) & 63u, kt = flat >> 12;
  const unsigned dd = 2u * kt + (l >> 5), col = nc * 32u + (l & 31u);
  const float* base = W + (size_t)(dd * 16u) * 2048u + col;
  unsigned wd[4];
#pragma unroll
  for (int wi = 0; wi < 4; ++wi) {
    unsigned v = 0;
#pragma unroll
    for (int bj = 0; bj < 4; ++bj) {
      float f = base[(size_t)(wi * 4 + bj) * 2048u];
      int q = (int)(f * 127.0f + 0.5f);
      q = q < 0 ? 0 : (q > 127 ? 127 : q);
      v |= (unsigned)q << (bj * 8);
    }
    wd[wi] = v;
  }
  uint4 o;
  o.x = wd[0]; o.y = wd[1]; o.z = wd[2]; o.w = wd[3];
  wfq[flat] = o;
}

// ---------------------------------------------------------------------------
// Kernel 3: zero-LDS streaming i8 GEMM, KP=1, depth-4 register pipeline.
// Block 256x32 (4 waves stacked in M), wave 64x32 (rf=2), NB=256 BK64 steps.
// Grid 512. Plain stores. NO setprio (the R15 ablation).
// ---------------------------------------------------------------------------
__global__ __launch_bounds__(256, 4) void k_gemm(const uint4* __restrict__ wfq,
                                                 const unsigned* __restrict__ chR,
                                                 float* __restrict__ out) {
  constexpr int NB = 256;  // BK64 steps, full K

  const int tid = threadIdx.x, lane = tid & 63;
  const int w = tid >> 6;  // wave index in M within block
  const unsigned q = (unsigned)(lane >> 5), q8 = q << 3;

  // XCD decode (512 = 8 XCD x 64): XCD owns 8 col-strips x all 8 mBlk.
  const unsigned orig = blockIdx.x;
  const unsigned xcd = orig & 7u, slot = orig >> 3;   // slot [0,64)
  const unsigned strip = xcd * 8u + (slot & 7u);      // [0,64) col strip (32 cols)
  const unsigned mBlk = slot >> 3;                    // [0,8) 256-row block

  // W fragment pointer: chunk (kt*64 + nc)*64 + lane, nc = strip, kt = 2*kq.
  // Step stride (kq+1) = 8192 uint4; second K32 half at +4096.
  const uint4* wp0 = wfq + ((size_t)strip * 64u) + lane;  // kt=0 base
  const uint4* wp1 = wp0 + 4096;
  // Channel pointer: uint2 per (kq, g, lane&31, rf-pair). g = mBlk*2 + (w>>1),
  // rf-pair = w&1. Step stride = 1024 uint2.
  const unsigned g = mBlk * 2u + ((unsigned)w >> 1);
  const uint2* cp = (const uint2*)chR +
                    (((size_t)g) * 32u + (lane & 31)) * 2u + ((unsigned)w & 1u);

  i32x16 acc[2] = {};

#define MFMA_I8(a, b, c) __builtin_amdgcn_mfma_i32_32x32x32_i8((a), (b), (c), 0, 0, 0)

  uint4 b0[4], b1[4];
  uint2 cq[4];
#pragma unroll
  for (int i = 0; i < 4; ++i) {
    b0[i] = wp0[(size_t)i * 8192];
    b1[i] = wp1[(size_t)i * 8192];
    cq[i] = cp[(size_t)i * 1024];
  }

#define COMPUTE(i)                                                        \
  {                                                                       \
    const i32x4 vb0 = *(const i32x4*)&b0[i];                              \
    const i32x4 vb1 = *(const i32x4*)&b1[i];                              \
    acc[0] = MFMA_I8(mkA((cq[i].x >> q8) & 15u), vb0, acc[0]);            \
    acc[1] = MFMA_I8(mkA((cq[i].y >> q8) & 15u), vb0, acc[1]);            \
    acc[0] = MFMA_I8(mkA((cq[i].x >> (16u + q8)) & 15u), vb1, acc[0]);    \
    acc[1] = MFMA_I8(mkA((cq[i].y >> (16u + q8)) & 15u), vb1, acc[1]);    \
  }
  // Refill buffer i for step p+4 (clamped at tail -> dead reload).
#define REFILL(i, p)                                                      \
  {                                                                       \
    const int np = ((p) + 4 < NB) ? (p) + 4 : (p);                        \
    b0[i] = wp0[(size_t)np * 8192];                                       \
    b1[i] = wp1[(size_t)np * 8192];                                       \
    cq[i] = cp[(size_t)np * 1024];                                        \
  }

  for (int p = 0; p < NB; p += 4) {
    COMPUTE(0) REFILL(0, p)
    COMPUTE(1) REFILL(1, p + 1)
    COMPUTE(2) REFILL(2, p + 2)
    COMPUTE(3) REFILL(3, p + 3)
  }
#undef COMPUTE
#undef REFILL

  // Epilogue: plain stores. C/D 32x32 layout: col = lane&31,
  // row = (reg&3) + 8*(reg>>2) + 4*q.
  const float scale = 1.0f / 127.0f;
  const int c = (int)strip * 32 + (lane & 31);
  const int rowW = (int)mBlk * 256 + w * 64;  // wave row origin
#pragma unroll
  for (int rf = 0; rf < 2; ++rf) {
    const int r0 = rowW + rf * 32 + (int)(q * 4u);
#pragma unroll
    for (int reg = 0; reg < 16; ++reg) {
      int r = r0 + (reg & 3) + 8 * (reg >> 2);
      out[(size_t)r * 2048 + c] = (float)acc[rf][reg] * scale;
    }
  }
}

// ---------------------------------------------------------------------------
// Fallback (ws too small): direct gather row-sum, one block per sample.
// ---------------------------------------------------------------------------
__global__ __launch_bounds__(256) void k_direct(const float* __restrict__ x,
                                                const int* __restrict__ anc,
                                                const float* __restrict__ W,
                                                float* __restrict__ out) {
  __shared__ unsigned rowoff[1024];
  const int b = blockIdx.x;
  const bool is64 = anchors_is_i64(anc);
  for (int d = threadIdx.x; d < 1024; d += 256) {
    unsigned ch = 0;
#pragma unroll
    for (int i = 0; i < 4; ++i) {
      int a = ld_anchor(anc, d * 4 + i, is64);
      ch |= (x[(size_t)b * 2048 + a] > 0.0f ? 1u : 0u) << i;
    }
    rowoff[d] = (unsigned)(d * 16 + ch) * 2048u;
  }
  __syncthreads();
  f32x4 a0 = {0.f, 0.f, 0.f, 0.f}, a1 = {0.f, 0.f, 0.f, 0.f};
  const int o0 = threadIdx.x * 4, o1 = 1024 + threadIdx.x * 4;
  for (int d = 0; d < 1024; ++d) {
    unsigned ro = rowoff[d];
    a0 += *(const f32x4*)(W + ro + o0);
    a1 += *(const f32x4*)(W + ro + o1);
  }
  *(f32x4*)(out + (size_t)b * 2048 + o0) = a0;
  *(f32x4*)(out + (size_t)b * 2048 + o1) = a1;
}

// ---------------------------------------------------------------------------
extern "C" void kernel_launch(void* const* d_in, const int* in_sizes, int n_in,
                              void* d_out, int out_size, void* d_ws, size_t ws_size,
                              hipStream_t stream) {
  const float* x = (const float*)d_in[0];
  const int* anc = (const int*)d_in[1];
  const float* W = (const float*)d_in[2];
  float* out = (float*)d_out;

  const size_t CHR_BYTES = 2ull * 1024 * 1024;   // chR: 256 x 16 x 32 uint4
  const size_t WFQ_BYTES = 32ull * 1024 * 1024;  // wfq: 2M x 16 B (i8)
  const size_t XBT_BYTES = 4ull * 1024 * 1024;   // xbT: 2048 x 2048 u8
  const size_t BASE = CHR_BYTES + WFQ_BYTES + XBT_BYTES;  // 38 MiB

  if (ws_size < BASE) {
    k_direct<<<2048, 256, 0, stream>>>(x, anc, W, out);
    return;
  }

  unsigned* chR = (unsigned*)d_ws;
  uint4* wfq = (uint4*)((char*)d_ws + CHR_BYTES);
  unsigned char* xbT = (unsigned char*)((char*)d_ws + CHR_BYTES + WFQ_BYTES);

  k_bits<<<dim3(32, 32), 256, 0, stream>>>(x, xbT);
  k_channels3<<<dim3(8, 256), 256, 0, stream>>>(xbT, anc, chR);
  k_wfrag_i8<<<8192, 256, 0, stream>>>(W, wfq);
  k_gemm<<<512, 256, 0, stream>>>(wfq, chR, out);
}

// Round 16
// 107.349 us; speedup vs baseline: 1.4692x; 1.2000x over previous
//
#include <hip/hip_runtime.h>
#include <hip/hip_bf16.h>

// LUTLayerBasic: out[b] = sum_d W[d*16 + ch(b,d)], ch = 4 sign bits of gathered x.
// R16: zero-LDS streaming i8 MFMA, rf=4 wave (128 rows x 32 cols) so each W
// fragment load feeds 4 MFMA (R12's rf=2 fed 2) -> vector-memory instructions
// and L1 bytes per MFMA halved (R12's diagnosed limiter). Block = 4 waves in
// N (128x128), grid 256 = 1 block/CU, KP=1, plain stores, depth-4 register
// prefetch WITH setprio (R15 showed removing it collapses the pipeline).
//
// Dims: B=2048, N_IN=2048, D=1024, A=4, O=2048, C=16, K=N_LUT=16384.

typedef __attribute__((ext_vector_type(4))) int i32x4;
typedef __attribute__((ext_vector_type(16))) int i32x16;
typedef __attribute__((ext_vector_type(4))) float f32x4;

__device__ __forceinline__ bool anchors_is_i64(const int* a) {
  int v = 0;
#pragma unroll
  for (int i = 0; i < 32; ++i) v |= a[2 * i + 1];
  return v == 0;
}

__device__ __forceinline__ int ld_anchor(const int* a, int i, bool is64) {
  return is64 ? a[2 * i] : a[i];
}

// One-hot A fragment: 16 bytes, byte[ch] = 1 (ch in [0,16)). R7/R8-verified.
__device__ __forceinline__ i32x4 mkA(unsigned ch) {
  unsigned long long v = 1ull << ((ch << 3) & 63u);
  union { unsigned long long q[2]; i32x4 v4; } u;
  u.q[0] = (ch < 8u) ? v : 0ull;
  u.q[1] = (ch < 8u) ? 0ull : v;
  return u.v4;
}

// ---------------------------------------------------------------------------
// Kernel 0: transpose + bitpack. xbT[n][s] = (x[s][n] > 0) as byte.
// ---------------------------------------------------------------------------
__global__ __launch_bounds__(256) void k_bits(const float* __restrict__ x,
                                              unsigned char* __restrict__ xbT) {
  __shared__ unsigned char t[64][65];
  const int tid = threadIdx.x;
  const int tr = blockIdx.x * 64, tc = blockIdx.y * 64;
  const int c = tid & 63, r0 = tid >> 6;
#pragma unroll
  for (int j = 0; j < 16; ++j) {
    int r = r0 + j * 4;
    t[c][r] = x[(size_t)(tr + r) * 2048 + tc + c] > 0.0f ? 1 : 0;
  }
  __syncthreads();
#pragma unroll
  for (int j = 0; j < 16; ++j) {
    int n = r0 + j * 4;
    xbT[(size_t)(tc + n) * 2048 + tr + c] = t[n][c];
  }
}

// ---------------------------------------------------------------------------
// Kernel 1: channel quads in GEMM-register layout. For sample s decomposed as
// s = g*128 + rf*32 + l (g row-group, rf row-frag, l lane):
//   chR[((kq*16 + g)*32 + l) * 4 + rf] = ch(s,4kq..4kq+3) packed bytes.
// ---------------------------------------------------------------------------
__global__ __launch_bounds__(256) void k_channels3(const unsigned char* __restrict__ xbT,
                                                   const int* __restrict__ anc,
                                                   unsigned* __restrict__ chR) {
  const int s = blockIdx.x * 256 + threadIdx.x;  // gridDim.x = 8
  const int kq = blockIdx.y;                     // [0, 256)
  const bool is64 = anchors_is_i64(anc);
  unsigned word = 0;
#pragma unroll
  for (int di = 0; di < 4; ++di) {
    const int d = kq * 4 + di;
    unsigned ch = 0;
#pragma unroll
    for (int i = 0; i < 4; ++i) {
      int a = ld_anchor(anc, d * 4 + i, is64);
      ch |= (unsigned)xbT[(size_t)a * 2048 + s] << i;
    }
    word |= ch << (di * 8);
  }
  const int g = s >> 7, rf = (s >> 5) & 3, l = s & 31;
  chR[(((size_t)kq * 16 + g) * 32 + l) * 4 + rf] = word;
}

// ---------------------------------------------------------------------------
// Kernel 2: W (f32 [16384][2048]) -> i8 fragment-linear chunks:
//   chunk c_idx = (kt*64 + nc)*64 + l  (16 B), byte j:
//   Wq[(2kt + (l>>5))*16 + j][nc*32 + (l&31)],  Wq = round(W*127).
// ---------------------------------------------------------------------------
__global__ __launch_bounds__(256) void k_wfrag_i8(const float* __restrict__ W,
                                                  uint4* __restrict__ wfq) {
  const unsigned flat = blockIdx.x * 256 + threadIdx.x;  // [0, 2097152)
  const unsigned l = flat & 63u, nc = (flat >> 6) & 63u, kt = flat >> 12;
  const unsigned dd = 2u * kt + (l >> 5), col = nc * 32u + (l & 31u);
  const float* base = W + (size_t)(dd * 16u) * 2048u + col;
  unsigned wd[4];
#pragma unroll
  for (int wi = 0; wi < 4; ++wi) {
    unsigned v = 0;
#pragma unroll
    for (int bj = 0; bj < 4; ++bj) {
      float f = base[(size_t)(wi * 4 + bj) * 2048u];
      int q = (int)(f * 127.0f + 0.5f);
      q = q < 0 ? 0 : (q > 127 ? 127 : q);
      v |= (unsigned)q << (bj * 8);
    }
    wd[wi] = v;
  }
  uint4 o;
  o.x = wd[0]; o.y = wd[1]; o.z = wd[2]; o.w = wd[3];
  wfq[flat] = o;
}

// ---------------------------------------------------------------------------
// Kernel 3: zero-LDS streaming i8 GEMM, rf=4 waves, KP=1, depth-4 pipeline.
// Block 128x128 (4 waves side-by-side in N), wave 128x32, NB=256 BK64 steps.
// Grid 256 (= 1 block/CU). Plain stores.
// ---------------------------------------------------------------------------
__global__ __launch_bounds__(256, 1) void k_gemm(const uint4* __restrict__ wfq,
                                                 const unsigned* __restrict__ chR,
                                                 float* __restrict__ out) {
  constexpr int NB = 256;  // BK64 steps, full K
  constexpr int PD = 4;    // prefetch depth

  const int tid = threadIdx.x, lane = tid & 63;
  const int w = tid >> 6;  // wave = column sub-slice [0,4)
  const unsigned q8 = (unsigned)(lane >> 5) << 3;

  // XCD decode (256 = 8 XCD x 32): XCD owns 2 nBlk panels (2 MB i8 each);
  // mBlk-adjacent so a panel's 16 blocks co-run -> panel L2-resident.
  const unsigned orig = blockIdx.x;
  const unsigned xcd = orig & 7u, slot = orig >> 3;   // slot [0,32)
  const unsigned nBlk = xcd * 2u + (slot >> 4);       // [0,16) 128-col block
  const unsigned mBlk = slot & 15u;                   // [0,16) 128-row block

  // W fragment pointer: chunk (kt*64 + nc)*64 + lane, nc = nBlk*4 + w.
  // BK64 step stride = 8192 uint4; second K32 half at +4096.
  const uint4* wp0 = wfq + ((size_t)(nBlk * 4u + (unsigned)w)) * 64u + lane;
  const uint4* wp1 = wp0 + 4096;
  // Channel pointer: uint4 per (kq, g=mBlk, lane&31); step stride 512 uint4.
  const uint4* cp = (const uint4*)chR + ((size_t)mBlk) * 32u + (lane & 31);

  i32x16 acc[4] = {};

#define MFMA_I8(a, b, c) __builtin_amdgcn_mfma_i32_32x32x32_i8((a), (b), (c), 0, 0, 0)

  uint4 b0[PD], b1[PD], cq[PD];
#pragma unroll
  for (int i = 0; i < PD; ++i) {
    b0[i] = wp0[(size_t)i * 8192];
    b1[i] = wp1[(size_t)i * 8192];
    cq[i] = cp[(size_t)i * 512];
  }

#define COMPUTE(i)                                                        \
  {                                                                       \
    const i32x4 vb0 = *(const i32x4*)&b0[i];                              \
    const i32x4 vb1 = *(const i32x4*)&b1[i];                              \
    __builtin_amdgcn_s_setprio(1);                                        \
    acc[0] = MFMA_I8(mkA((cq[i].x >> q8) & 15u), vb0, acc[0]);            \
    acc[1] = MFMA_I8(mkA((cq[i].y >> q8) & 15u), vb0, acc[1]);            \
    acc[2] = MFMA_I8(mkA((cq[i].z >> q8) & 15u), vb0, acc[2]);            \
    acc[3] = MFMA_I8(mkA((cq[i].w >> q8) & 15u), vb0, acc[3]);            \
    acc[0] = MFMA_I8(mkA((cq[i].x >> (16u + q8)) & 15u), vb1, acc[0]);    \
    acc[1] = MFMA_I8(mkA((cq[i].y >> (16u + q8)) & 15u), vb1, acc[1]);    \
    acc[2] = MFMA_I8(mkA((cq[i].z >> (16u + q8)) & 15u), vb1, acc[2]);    \
    acc[3] = MFMA_I8(mkA((cq[i].w >> (16u + q8)) & 15u), vb1, acc[3]);    \
    __builtin_amdgcn_s_setprio(0);                                        \
  }
  // Refill buffer i for step p+PD (clamped at tail -> dead reload).
#define REFILL(i, p)                                                      \
  {                                                                       \
    const int np = ((p) + PD < NB) ? (p) + PD : (p);                      \
    b0[i] = wp0[(size_t)np * 8192];                                       \
    b1[i] = wp1[(size_t)np * 8192];                                       \
    cq[i] = cp[(size_t)np * 512];                                         \
  }

  for (int p = 0; p < NB; p += PD) {
    COMPUTE(0) REFILL(0, p)
    COMPUTE(1) REFILL(1, p + 1)
    COMPUTE(2) REFILL(2, p + 2)
    COMPUTE(3) REFILL(3, p + 3)
  }
#undef COMPUTE
#undef REFILL

  // Epilogue: plain stores. C/D 32x32 layout: col=lane&31,
  // row = (reg&3) + 8*(reg>>2) + 4*(lane>>5).
  const float scale = 1.0f / 127.0f;
  const int c = (int)nBlk * 128 + w * 32 + (lane & 31);
#pragma unroll
  for (int rf = 0; rf < 4; ++rf) {
    const int r0 = (int)mBlk * 128 + rf * 32 + (int)((unsigned)(lane >> 5) * 4u);
#pragma unroll
    for (int reg = 0; reg < 16; ++reg) {
      int r = r0 + (reg & 3) + 8 * (reg >> 2);
      out[(size_t)r * 2048 + c] = (float)acc[rf][reg] * scale;
    }
  }
}

// ---------------------------------------------------------------------------
// Fallback (ws too small): direct gather row-sum, one block per sample.
// ---------------------------------------------------------------------------
__global__ __launch_bounds__(256) void k_direct(const float* __restrict__ x,
                                                const int* __restrict__ anc,
                                                const float* __restrict__ W,
                                                float* __restrict__ out) {
  __shared__ unsigned rowoff[1024];
  const int b = blockIdx.x;
  const bool is64 = anchors_is_i64(anc);
  for (int d = threadIdx.x; d < 1024; d += 256) {
    unsigned ch = 0;
#pragma unroll
    for (int i = 0; i < 4; ++i) {
      int a = ld_anchor(anc, d * 4 + i, is64);
      ch |= (x[(size_t)b * 2048 + a] > 0.0f ? 1u : 0u) << i;
    }
    rowoff[d] = (unsigned)(d * 16 + ch) * 2048u;
  }
  __syncthreads();
  f32x4 a0 = {0.f, 0.f, 0.f, 0.f}, a1 = {0.f, 0.f, 0.f, 0.f};
  const int o0 = threadIdx.x * 4, o1 = 1024 + threadIdx.x * 4;
  for (int d = 0; d < 1024; ++d) {
    unsigned ro = rowoff[d];
    a0 += *(const f32x4*)(W + ro + o0);
    a1 += *(const f32x4*)(W + ro + o1);
  }
  *(f32x4*)(out + (size_t)b * 2048 + o0) = a0;
  *(f32x4*)(out + (size_t)b * 2048 + o1) = a1;
}

// ---------------------------------------------------------------------------
extern "C" void kernel_launch(void* const* d_in, const int* in_sizes, int n_in,
                              void* d_out, int out_size, void* d_ws, size_t ws_size,
                              hipStream_t stream) {
  const float* x = (const float*)d_in[0];
  const int* anc = (const int*)d_in[1];
  const float* W = (const float*)d_in[2];
  float* out = (float*)d_out;

  const size_t CHR_BYTES = 2ull * 1024 * 1024;   // chR: 256 x 16 x 32 uint4
  const size_t WFQ_BYTES = 32ull * 1024 * 1024;  // wfq: 2M x 16 B (i8)
  const size_t XBT_BYTES = 4ull * 1024 * 1024;   // xbT: 2048 x 2048 u8
  const size_t BASE = CHR_BYTES + WFQ_BYTES + XBT_BYTES;  // 38 MiB

  if (ws_size < BASE) {
    k_direct<<<2048, 256, 0, stream>>>(x, anc, W, out);
    return;
  }

  unsigned* chR = (unsigned*)d_ws;
  uint4* wfq = (uint4*)((char*)d_ws + CHR_BYTES);
  unsigned char* xbT = (unsigned char*)((char*)d_ws + CHR_BYTES + WFQ_BYTES);

  k_bits<<<dim3(32, 32), 256, 0, stream>>>(x, xbT);
  k_channels3<<<dim3(8, 256), 256, 0, stream>>>(xbT, anc, chR);
  k_wfrag_i8<<<8192, 256, 0, stream>>>(W, wfq);
  k_gemm<<<256, 256, 0, stream>>>(wfq, chR, out);
}

// Round 17
// 100.786 us; speedup vs baseline: 1.5649x; 1.0651x over previous
//
#include <hip/hip_runtime.h>
#include <hip/hip_bf16.h>

// LUTLayerBasic: out[b] = sum_d W[d*16 + ch(b,d)], ch = 4 sign bits of gathered x.
// R17 = R12 (best shape: wave 64x32 rf=2, block 256x32, grid 512, KP=1, plain
// stores, depth-4 prefetch + setprio) with A-build moved VALU -> LDS:
//  - 256 B LDS LUT: entry c = one-hot i8 A-fragment (byte[c]=1). One
//    ds_read_b128 replaces ~10 VALU ops per fragment. Max 2-way bank alias
//    (free, m136); same-entry reads broadcast.
//  - chR prep stores ch<<4 per byte -> GEMM address = extract + add.
//  - A-fragments pipelined one step ahead (afA/afB ping-pong) so ds_reads
//    hide under the previous step's MFMA cluster.
//
// Dims: B=2048, N_IN=2048, D=1024, A=4, O=2048, C=16, K=N_LUT=16384.

typedef __attribute__((ext_vector_type(4))) int i32x4;
typedef __attribute__((ext_vector_type(16))) int i32x16;
typedef __attribute__((ext_vector_type(4))) float f32x4;

__device__ __forceinline__ bool anchors_is_i64(const int* a) {
  int v = 0;
#pragma unroll
  for (int i = 0; i < 32; ++i) v |= a[2 * i + 1];
  return v == 0;
}

__device__ __forceinline__ int ld_anchor(const int* a, int i, bool is64) {
  return is64 ? a[2 * i] : a[i];
}

// ---------------------------------------------------------------------------
// Kernel 0: transpose + bitpack. xbT[n][s] = (x[s][n] > 0) as byte.
// ---------------------------------------------------------------------------
__global__ __launch_bounds__(256) void k_bits(const float* __restrict__ x,
                                              unsigned char* __restrict__ xbT) {
  __shared__ unsigned char t[64][65];
  const int tid = threadIdx.x;
  const int tr = blockIdx.x * 64, tc = blockIdx.y * 64;
  const int c = tid & 63, r0 = tid >> 6;
#pragma unroll
  for (int j = 0; j < 16; ++j) {
    int r = r0 + j * 4;
    t[c][r] = x[(size_t)(tr + r) * 2048 + tc + c] > 0.0f ? 1 : 0;
  }
  __syncthreads();
#pragma unroll
  for (int j = 0; j < 16; ++j) {
    int n = r0 + j * 4;
    xbT[(size_t)(tc + n) * 2048 + tr + c] = t[n][c];
  }
}

// ---------------------------------------------------------------------------
// Kernel 1: channel quads in GEMM-register layout, PRE-SHIFTED (ch<<4).
// For s = g*128 + rf*32 + l: chR[((kq*16+g)*32+l)*4 + rf] has byte di =
// ch(s, 4kq+di) * 16  (LDS LUT byte offset, values 0..240).
// ---------------------------------------------------------------------------
__global__ __launch_bounds__(256) void k_channels3(const unsigned char* __restrict__ xbT,
                                                   const int* __restrict__ anc,
                                                   unsigned* __restrict__ chR) {
  const int s = blockIdx.x * 256 + threadIdx.x;  // gridDim.x = 8
  const int kq = blockIdx.y;                     // [0, 256)
  const bool is64 = anchors_is_i64(anc);
  unsigned word = 0;
#pragma unroll
  for (int di = 0; di < 4; ++di) {
    const int d = kq * 4 + di;
    unsigned ch = 0;
#pragma unroll
    for (int i = 0; i < 4; ++i) {
      int a = ld_anchor(anc, d * 4 + i, is64);
      ch |= (unsigned)xbT[(size_t)a * 2048 + s] << i;
    }
    word |= (ch << 4) << (di * 8);
  }
  const int g = s >> 7, rf = (s >> 5) & 3, l = s & 31;
  chR[(((size_t)kq * 16 + g) * 32 + l) * 4 + rf] = word;
}

// ---------------------------------------------------------------------------
// Kernel 2: W (f32 [16384][2048]) -> i8 fragment-linear chunks:
//   chunk c_idx = (kt*64 + nc)*64 + l  (16 B), byte j:
//   Wq[(2kt + (l>>5))*16 + j][nc*32 + (l&31)],  Wq = round(W*127).
// ---------------------------------------------------------------------------
__global__ __launch_bounds__(256) void k_wfrag_i8(const float* __restrict__ W,
                                                  uint4* __restrict__ wfq) {
  const unsigned flat = blockIdx.x * 256 + threadIdx.x;  // [0, 2097152)
  const unsigned l = flat & 63u, nc = (flat >> 6) & 63u, kt = flat >> 12;
  const unsigned dd = 2u * kt + (l >> 5), col = nc * 32u + (l & 31u);
  const float* base = W + (size_t)(dd * 16u) * 2048u + col;
  unsigned wd[4];
#pragma unroll
  for (int wi = 0; wi < 4; ++wi) {
    unsigned v = 0;
#pragma unroll
    for (int bj = 0; bj < 4; ++bj) {
      float f = base[(size_t)(wi * 4 + bj) * 2048u];
      int q = (int)(f * 127.0f + 0.5f);
      q = q < 0 ? 0 : (q > 127 ? 127 : q);
      v |= (unsigned)q << (bj * 8);
    }
    wd[wi] = v;
  }
  uint4 o;
  o.x = wd[0]; o.y = wd[1]; o.z = wd[2]; o.w = wd[3];
  wfq[flat] = o;
}

// ---------------------------------------------------------------------------
// Kernel 3: streaming i8 GEMM, LDS one-hot LUT for A. KP=1, depth-4 register
// prefetch, A-frag 1-step lookahead. Block 256x32 (4 waves in M), wave 64x32
// (rf=2), NB=256 BK64 steps. Grid 512. Plain stores.
// ---------------------------------------------------------------------------
__global__ __launch_bounds__(256, 2) void k_gemm(const uint4* __restrict__ wfq,
                                                 const unsigned* __restrict__ chR,
                                                 float* __restrict__ out) {
  constexpr int NB = 256;  // BK64 steps, full K
  __shared__ __align__(16) unsigned lut[16][4];  // entry c: one-hot i8 frag

  const int tid = threadIdx.x, lane = tid & 63;
  const int w = tid >> 6;  // wave index in M within block
  const unsigned q = (unsigned)(lane >> 5), q8 = q << 3;

  // Build LUT: entry e, dword d: byte b set iff d*4+b == e.
  if (tid < 64) {
    int e = tid >> 2, d = tid & 3;
    unsigned v = 0;
    int base = d * 4;
    if (e >= base && e < base + 4) v = 1u << ((e - base) * 8);
    lut[e][d] = v;
  }
  __syncthreads();
  const char* lutb = (const char*)lut;

  // XCD decode (512 = 8 XCD x 64): XCD owns 8 col-strips x all 8 mBlk.
  const unsigned orig = blockIdx.x;
  const unsigned xcd = orig & 7u, slot = orig >> 3;   // slot [0,64)
  const unsigned strip = xcd * 8u + (slot & 7u);      // [0,64) col strip (32 cols)
  const unsigned mBlk = slot >> 3;                    // [0,8) 256-row block

  // W fragment pointer: chunk (kt*64 + nc)*64 + lane, nc = strip, kt = 2*kq.
  // Step stride = 8192 uint4; second K32 half at +4096.
  const uint4* wp0 = wfq + ((size_t)strip * 64u) + lane;
  const uint4* wp1 = wp0 + 4096;
  // Channel pointer: uint2 per (kq, g, lane&31, rf-pair). g = mBlk*2 + (w>>1),
  // rf-pair = w&1. Step stride = 1024 uint2.
  const unsigned g = mBlk * 2u + ((unsigned)w >> 1);
  const uint2* cp = (const uint2*)chR +
                    (((size_t)g) * 32u + (lane & 31)) * 2u + ((unsigned)w & 1u);

  i32x16 acc[2] = {};

#define MFMA_I8(a, b, c) __builtin_amdgcn_mfma_i32_32x32x32_i8((a), (b), (c), 0, 0, 0)

  uint4 b0[4], b1[4];
  uint2 cq[4];
#pragma unroll
  for (int i = 0; i < 4; ++i) {
    b0[i] = wp0[(size_t)i * 8192];
    b1[i] = wp1[(size_t)i * 8192];
    cq[i] = cp[(size_t)i * 1024];
  }

  i32x4 afA[4], afB[4];

  // Load the 4 A-fragments for buffer i's step from the LDS LUT.
#define LOADA(af, i)                                                      \
  {                                                                       \
    unsigned a0 = (cq[i].x >> q8) & 0xFFu;                                \
    unsigned a1 = (cq[i].y >> q8) & 0xFFu;                                \
    unsigned a2 = (cq[i].x >> (16u + q8)) & 0xFFu;                        \
    unsigned a3 = (cq[i].y >> (16u + q8)) & 0xFFu;                        \
    af[0] = *(const i32x4*)(lutb + a0);                                   \
    af[1] = *(const i32x4*)(lutb + a1);                                   \
    af[2] = *(const i32x4*)(lutb + a2);                                   \
    af[3] = *(const i32x4*)(lutb + a3);                                   \
  }

#define COMPUTE(i, af)                                                    \
  {                                                                       \
    const i32x4 vb0 = *(const i32x4*)&b0[i];                              \
    const i32x4 vb1 = *(const i32x4*)&b1[i];                              \
    __builtin_amdgcn_s_setprio(1);                                        \
    acc[0] = MFMA_I8(af[0], vb0, acc[0]);                                 \
    acc[1] = MFMA_I8(af[1], vb0, acc[1]);                                 \
    acc[0] = MFMA_I8(af[2], vb1, acc[0]);                                 \
    acc[1] = MFMA_I8(af[3], vb1, acc[1]);                                 \
    __builtin_amdgcn_s_setprio(0);                                        \
  }
  // Refill buffer i for step p+4 (clamped at tail -> dead reload).
#define REFILL(i, p)                                                      \
  {                                                                       \
    const int np = ((p) + 4 < NB) ? (p) + 4 : (p);                        \
    b0[i] = wp0[(size_t)np * 8192];                                       \
    b1[i] = wp1[(size_t)np * 8192];                                       \
    cq[i] = cp[(size_t)np * 1024];                                        \
  }

  LOADA(afA, 0)
  for (int p = 0; p < NB; p += 4) {
    LOADA(afB, 1)
    COMPUTE(0, afA) REFILL(0, p)
    LOADA(afA, 2)
    COMPUTE(1, afB) REFILL(1, p + 1)
    LOADA(afB, 3)
    COMPUTE(2, afA) REFILL(2, p + 2)
    LOADA(afA, 0)   // step p+4 (cq[0] refilled above); tail: unused
    COMPUTE(3, afB) REFILL(3, p + 3)
  }
#undef LOADA
#undef COMPUTE
#undef REFILL

  // Epilogue: plain stores. C/D 32x32 layout: col = lane&31,
  // row = (reg&3) + 8*(reg>>2) + 4*q.
  const float scale = 1.0f / 127.0f;
  const int c = (int)strip * 32 + (lane & 31);
  const int rowW = (int)mBlk * 256 + w * 64;  // wave row origin
#pragma unroll
  for (int rf = 0; rf < 2; ++rf) {
    const int r0 = rowW + rf * 32 + (int)(q * 4u);
#pragma unroll
    for (int reg = 0; reg < 16; ++reg) {
      int r = r0 + (reg & 3) + 8 * (reg >> 2);
      out[(size_t)r * 2048 + c] = (float)acc[rf][reg] * scale;
    }
  }
}

// ---------------------------------------------------------------------------
// Fallback (ws too small): direct gather row-sum, one block per sample.
// ---------------------------------------------------------------------------
__global__ __launch_bounds__(256) void k_direct(const float* __restrict__ x,
                                                const int* __restrict__ anc,
                                                const float* __restrict__ W,
                                                float* __restrict__ out) {
  __shared__ unsigned rowoff[1024];
  const int b = blockIdx.x;
  const bool is64 = anchors_is_i64(anc);
  for (int d = threadIdx.x; d < 1024; d += 256) {
    unsigned ch = 0;
#pragma unroll
    for (int i = 0; i < 4; ++i) {
      int a = ld_anchor(anc, d * 4 + i, is64);
      ch |= (x[(size_t)b * 2048 + a] > 0.0f ? 1u : 0u) << i;
    }
    rowoff[d] = (unsigned)(d * 16 + ch) * 2048u;
  }
  __syncthreads();
  f32x4 a0 = {0.f, 0.f, 0.f, 0.f}, a1 = {0.f, 0.f, 0.f, 0.f};
  const int o0 = threadIdx.x * 4, o1 = 1024 + threadIdx.x * 4;
  for (int d = 0; d < 1024; ++d) {
    unsigned ro = rowoff[d];
    a0 += *(const f32x4*)(W + ro + o0);
    a1 += *(const f32x4*)(W + ro + o1);
  }
  *(f32x4*)(out + (size_t)b * 2048 + o0) = a0;
  *(f32x4*)(out + (size_t)b * 2048 + o1) = a1;
}

// ---------------------------------------------------------------------------
extern "C" void kernel_launch(void* const* d_in, const int* in_sizes, int n_in,
                              void* d_out, int out_size, void* d_ws, size_t ws_size,
                              hipStream_t stream) {
  const float* x = (const float*)d_in[0];
  const int* anc = (const int*)d_in[1];
  const float* W = (const float*)d_in[2];
  float* out = (float*)d_out;

  const size_t CHR_BYTES = 2ull * 1024 * 1024;   // chR: 256 x 16 x 32 uint4
  const size_t WFQ_BYTES = 32ull * 1024 * 1024;  // wfq: 2M x 16 B (i8)
  const size_t XBT_BYTES = 4ull * 1024 * 1024;   // xbT: 2048 x 2048 u8
  const size_t BASE = CHR_BYTES + WFQ_BYTES + XBT_BYTES;  // 38 MiB

  if (ws_size < BASE) {
    k_direct<<<2048, 256, 0, stream>>>(x, anc, W, out);
    return;
  }

  unsigned* chR = (unsigned*)d_ws;
  uint4* wfq = (uint4*)((char*)d_ws + CHR_BYTES);
  unsigned char* xbT = (unsigned char*)((char*)d_ws + CHR_BYTES + WFQ_BYTES);

  k_bits<<<dim3(32, 32), 256, 0, stream>>>(x, xbT);
  k_channels3<<<dim3(8, 256), 256, 0, stream>>>(xbT, anc, chR);
  k_wfrag_i8<<<8192, 256, 0, stream>>>(W, wfq);
  k_gemm<<<512, 256, 0, stream>>>(wfq, chR, out);
}